// Round 1
// baseline (111.566 us; speedup 1.0000x reference)
//
#include <hip/hip_runtime.h>

// out[b,o,d,s] = sum_i x[b,i] * peso[o,i,d,s] * mask[o,i]
// B=256, IN=1024, OUT=512, D*S=128, mask ~10% nonzero.
//
// Strategy: exploit sparsity. ws holds xT (transposed x) + per-o compacted
// nonzero index lists. Main kernel: one block per (o, 64-row b-tile); lane->b
// so x loads are coalesced; w row (128 floats) is wave-uniform -> scalar loads.

#define B_   256
#define IN_  1024
#define OUT_ 512
#define DS_  128

// ws layout:
//   [0, 1 MiB)            xT  float[IN_][B_]
//   [1 MiB, 1 MiB+2 KiB)  cnt int[OUT_]
//   [1 MiB+4 KiB, +1 MiB) idx unsigned short[OUT_][IN_]

__global__ __launch_bounds__(256) void transpose_x(const float* __restrict__ x,
                                                   float* __restrict__ xT) {
    __shared__ float tile[64][65];
    int t  = threadIdx.x;
    int c  = t & 63;
    int r0 = t >> 6;                      // 0..3
    int i0 = (blockIdx.x & 15) * 64;      // 16 i-tiles
    int b0 = (blockIdx.x >> 4) * 64;      // 4 b-tiles
#pragma unroll
    for (int k = 0; k < 16; ++k) {
        int r = r0 + k * 4;
        tile[r][c] = x[(size_t)(b0 + r) * IN_ + i0 + c];
    }
    __syncthreads();
#pragma unroll
    for (int k = 0; k < 16; ++k) {
        int r = r0 + k * 4;               // row within i-tile
        xT[(size_t)(i0 + r) * B_ + b0 + c] = tile[c][r];
    }
}

__global__ __launch_bounds__(256) void build_idx(const float* __restrict__ mask,
                                                 int* __restrict__ cnt,
                                                 unsigned short* __restrict__ idx) {
    int o    = blockIdx.x;
    int t    = threadIdx.x;
    int lane = t & 63;
    int wv   = t >> 6;
    const float* mrow = mask + (size_t)o * IN_;

    unsigned short loc[4];
    int c = 0;
    int ibase = t * 4;
#pragma unroll
    for (int k = 0; k < 4; ++k) {
        if (mrow[ibase + k] != 0.0f) loc[c++] = (unsigned short)(ibase + k);
    }
    // wave-level inclusive scan of counts
    int v = c;
#pragma unroll
    for (int off = 1; off < 64; off <<= 1) {
        int u = __shfl_up(v, off, 64);
        if (lane >= off) v += u;
    }
    __shared__ int wsum[4];
    if (lane == 63) wsum[wv] = v;
    __syncthreads();
    int base = 0;
    for (int w = 0; w < wv; ++w) base += wsum[w];
    int excl = base + v - c;

    unsigned short* orow = idx + (size_t)o * IN_;
    for (int k = 0; k < c; ++k) orow[excl + k] = loc[k];
    if (t == 255) cnt[o] = base + v;
}

__global__ __launch_bounds__(256) void spmm_kernel(const float* __restrict__ xT,
                                                   const float* __restrict__ peso,
                                                   const float* __restrict__ mask,
                                                   const int* __restrict__ cnt,
                                                   const unsigned short* __restrict__ idx,
                                                   float* __restrict__ out) {
    int bid  = blockIdx.x;
    int bt   = bid & 3;          // b-tile 0..3
    int o    = bid >> 2;         // 0..511
    int t    = threadIdx.x;
    int lane = t & 63;           // -> b within tile
    int dsc  = __builtin_amdgcn_readfirstlane(t >> 6);  // wave-uniform ds-chunk 0..3
    int b0   = bt * 64;

    float acc[32];
#pragma unroll
    for (int k = 0; k < 32; ++k) acc[k] = 0.0f;

    int n = cnt[o];
    const unsigned short* irow = idx + (size_t)o * IN_;
    const float* mrow  = mask + (size_t)o * IN_;
    const float* wbase = peso + (size_t)o * IN_ * DS_ + dsc * 32;
    const float* xbase = xT + b0 + lane;

    for (int j = 0; j < n; ++j) {
        int   i  = (int)irow[j];                 // block-uniform
        float m  = mrow[i];                      // block-uniform (==1.0 for kept)
        float xv = xbase[(size_t)i * B_] * m;    // coalesced 256B wave load
        const float4* wp = (const float4*)(wbase + (size_t)i * DS_);  // wave-uniform
#pragma unroll
        for (int q = 0; q < 8; ++q) {
            float4 w = wp[q];
            acc[q * 4 + 0] += xv * w.x;
            acc[q * 4 + 1] += xv * w.y;
            acc[q * 4 + 2] += xv * w.z;
            acc[q * 4 + 3] += xv * w.w;
        }
    }

    float* op = out + (size_t)(b0 + lane) * (OUT_ * DS_) + o * DS_ + dsc * 32;
#pragma unroll
    for (int q = 0; q < 8; ++q) {
        ((float4*)op)[q] = make_float4(acc[q * 4 + 0], acc[q * 4 + 1],
                                       acc[q * 4 + 2], acc[q * 4 + 3]);
    }
}

extern "C" void kernel_launch(void* const* d_in, const int* in_sizes, int n_in,
                              void* d_out, int out_size, void* d_ws, size_t ws_size,
                              hipStream_t stream) {
    const float* x    = (const float*)d_in[0];
    const float* peso = (const float*)d_in[1];
    const float* mask = (const float*)d_in[2];
    float* out = (float*)d_out;

    char* ws = (char*)d_ws;
    float*          xT  = (float*)ws;
    int*            cnt = (int*)(ws + (1 << 20));
    unsigned short* idx = (unsigned short*)(ws + (1 << 20) + 4096);

    transpose_x<<<64, 256, 0, stream>>>(x, xT);
    build_idx<<<OUT_, 256, 0, stream>>>(mask, cnt, idx);
    spmm_kernel<<<OUT_ * 4, 256, 0, stream>>>(xT, peso, mask, cnt, idx, out);
}

// Round 2
// 72.046 us; speedup vs baseline: 1.5485x; 1.5485x over previous
//
#include <hip/hip_runtime.h>

// out[b,o,ds] = sum_i x[b,i] * peso[o,i,ds] for i where mask[o,i]==1
// B=256, IN=1024, OUT=512, DS=128, ~10% of (o,i) kept. mask values are {0,1}
// exactly, so compaction subsumes the multiply.
//
// spmm mapping: block=(o, b-tile of 64). wave w -> 16 consecutive b rows;
// lane -> float2 of the ds axis (coalesced weight loads AND output stores).
// x values are wave-uniform -> scalar loads via readfirstlane'd index.

#define B_   256
#define IN_  1024
#define OUT_ 512
#define DS_  128

typedef float f16v __attribute__((ext_vector_type(16)));

// ws layout:
//   [0, 1 MiB)                  xT  float[IN_][B_]
//   [1 MiB, +2 KiB)             cnt int[OUT_]
//   [1 MiB + 4 KiB, +2 MiB)     idx int[OUT_][IN_]

__global__ __launch_bounds__(256) void transpose_x(const float* __restrict__ x,
                                                   float* __restrict__ xT) {
    __shared__ float tile[64][65];
    int t  = threadIdx.x;
    int c  = t & 63;
    int r0 = t >> 6;
    int i0 = (blockIdx.x & 15) * 64;
    int b0 = (blockIdx.x >> 4) * 64;
#pragma unroll
    for (int k = 0; k < 16; ++k) {
        int r = r0 + k * 4;
        tile[r][c] = x[(size_t)(b0 + r) * IN_ + i0 + c];
    }
    __syncthreads();
#pragma unroll
    for (int k = 0; k < 16; ++k) {
        int r = r0 + k * 4;
        xT[(size_t)(i0 + r) * B_ + b0 + c] = tile[c][r];
    }
}

__global__ __launch_bounds__(256) void build_idx(const float* __restrict__ mask,
                                                 int* __restrict__ cnt,
                                                 int* __restrict__ idx) {
    int o    = blockIdx.x;
    int t    = threadIdx.x;
    int lane = t & 63;
    int wv   = t >> 6;
    const float* mrow = mask + (size_t)o * IN_;

    int loc[4];
    int c = 0;
    int ibase = t * 4;
#pragma unroll
    for (int k = 0; k < 4; ++k) {
        if (mrow[ibase + k] != 0.0f) loc[c++] = ibase + k;
    }
    int v = c;
#pragma unroll
    for (int off = 1; off < 64; off <<= 1) {
        int u = __shfl_up(v, off, 64);
        if (lane >= off) v += u;
    }
    __shared__ int wsum[4];
    if (lane == 63) wsum[wv] = v;
    __syncthreads();
    int base = 0;
    for (int w = 0; w < wv; ++w) base += wsum[w];
    int excl = base + v - c;

    int* orow = idx + (size_t)o * IN_;
    for (int k = 0; k < c; ++k) orow[excl + k] = loc[k];
    if (t == 255) cnt[o] = base + v;
}

__global__ __launch_bounds__(256) void spmm_kernel(const float* __restrict__ xT,
                                                   const float* __restrict__ peso,
                                                   const int* __restrict__ cnt,
                                                   const int* __restrict__ idx,
                                                   float* __restrict__ out) {
    int bid  = blockIdx.x;
    int o    = bid & (OUT_ - 1);          // bid%8 == o%8 for every bt -> same XCD L2
    int bt   = bid >> 9;                  // 0..3
    int t    = threadIdx.x;
    int lane = t & 63;
    int wv   = __builtin_amdgcn_readfirstlane(t >> 6);
    int b0   = bt * 64 + wv * 16;         // this wave's 16 b rows

    float2 acc[16];
#pragma unroll
    for (int k = 0; k < 16; ++k) acc[k] = make_float2(0.0f, 0.0f);

    int n = cnt[o];
    const int*    irow  = idx + (size_t)o * IN_;
    const float2* wlane = (const float2*)(peso + (size_t)o * IN_ * DS_) + lane;
    const float*  xb    = xT + b0;

#pragma unroll 2
    for (int j = 0; j < n; ++j) {
        int i = __builtin_amdgcn_readfirstlane(irow[j]);
        float2 w = wlane[(size_t)i * (DS_ / 2)];              // coalesced 512B/wave
        f16v xs = *(const f16v*)(xb + (size_t)i * B_);        // wave-uniform -> s_load
#pragma unroll
        for (int k = 0; k < 16; ++k) {
            acc[k].x = fmaf(xs[k], w.x, acc[k].x);
            acc[k].y = fmaf(xs[k], w.y, acc[k].y);
        }
    }

    float* obase = out + (size_t)b0 * (OUT_ * DS_) + o * DS_ + 2 * lane;
#pragma unroll
    for (int k = 0; k < 16; ++k) {
        *(float2*)(obase + (size_t)k * (OUT_ * DS_)) = acc[k];  // 512B/wave contiguous
    }
}

extern "C" void kernel_launch(void* const* d_in, const int* in_sizes, int n_in,
                              void* d_out, int out_size, void* d_ws, size_t ws_size,
                              hipStream_t stream) {
    const float* x    = (const float*)d_in[0];
    const float* peso = (const float*)d_in[1];
    const float* mask = (const float*)d_in[2];
    float* out = (float*)d_out;

    char* ws = (char*)d_ws;
    float* xT  = (float*)ws;
    int*   cnt = (int*)(ws + (1 << 20));
    int*   idx = (int*)(ws + (1 << 20) + 4096);

    transpose_x<<<64, 256, 0, stream>>>(x, xT);
    build_idx<<<OUT_, 256, 0, stream>>>(mask, cnt, idx);
    spmm_kernel<<<OUT_ * 4, 256, 0, stream>>>(xT, peso, cnt, idx, out);
}